// Round 4
// baseline (373.571 us; speedup 1.0000x reference)
//
#include <hip/hip_runtime.h>
#include <hip/hip_bf16.h>
#include <stdint.h>

#define NPTS 8192
#define KSPLIT 16   // K split for aggregation; zp has KSPLIT partial buffers

typedef float f32x4 __attribute__((ext_vector_type(4)));
typedef short s16x8 __attribute__((ext_vector_type(8)));

// bf16 round-to-nearest-even
__device__ __forceinline__ unsigned short f2bf(float f) {
    unsigned int u = __builtin_bit_cast(unsigned int, f);
    u += 0x7FFFu + ((u >> 16) & 1u);
    return (unsigned short)(u >> 16);
}

// Y in exact MFMA-B-fragment order (16x16x32 bf16):
// frag unit (kb, ct, lane L=quad*16+n): 8 elems k=kb*32+quad*8+t, col=ct*16+n,
// flat uint4 index = (kb*4 + ct)*64 + L. A wave's (kb,ct) read = contiguous 1KB.

// ---------- kernel 1: mask floats + packed bits + dinv + Y1 (fused) ----------
// grid 512 x 256; block owns 16 rows. SoA LDS (conflict-free), it-outer loop
// (xj loaded once per chunk, reused by 4 rows). Y1 fused: block's 16 rows are
// exactly 2 quads of one Y kb-block.
__global__ __launch_bounds__(256) void k_mask(const float* __restrict__ states,
                                              const float* __restrict__ W1,
                                              float* __restrict__ mout,
                                              unsigned long long* __restrict__ maskb,
                                              float* __restrict__ dinv,
                                              uint4* __restrict__ y1) {
    __shared__ float xs[NPTS];  // 32 KB
    __shared__ float ys[NPTS];  // 32 KB
    __shared__ float dls[16];
    int tid = threadIdx.x;
    for (int r = tid; r < NPTS; r += 256) {
        float4 s = ((const float4*)states)[r];
        xs[r] = s.x; ys[r] = s.y;
    }
    __syncthreads();
    int wv = tid >> 6, L = tid & 63;
    int rowbase = blockIdx.x * 16 + wv * 4;
    float xi[4], yi[4];
    int deg[4] = {0, 0, 0, 0};
#pragma unroll
    for (int rr = 0; rr < 4; ++rr) { xi[rr] = xs[rowbase + rr]; yi[rr] = ys[rowbase + rr]; }
    for (int it = 0; it < 128; ++it) {
        int j = it * 64 + L;
        float xj = xs[j], yj = ys[j];
#pragma unroll
        for (int rr = 0; rr < 4; ++rr) {
            float dx = xi[rr] - xj;
            float dy = yi[rr] - yj;
            // must match numpy fp32 (dx*dx)+(dy*dy), no FMA contraction:
            float d2 = __fadd_rn(__fmul_rn(dx, dx), __fmul_rn(dy, dy));
            bool pred = (d2 <= 1.0f);
            __builtin_nontemporal_store(pred ? 1.0f : 0.0f,
                                        &mout[(size_t)(rowbase + rr) * NPTS + j]);
            unsigned long long b = __ballot(pred);
            if (L == 0) maskb[(size_t)(rowbase + rr) * 128 + it] = b;
            deg[rr] += (int)__popcll(b);
        }
    }
    if (L == 0) {
#pragma unroll
        for (int rr = 0; rr < 4; ++rr) {
            float dv = rsqrtf((float)deg[rr]);
            dinv[rowbase + rr] = dv;
            dls[wv * 4 + rr] = dv;
        }
    }
    __syncthreads();
    // Y1 phase: 128 threads produce the block's 128 uint4 fragments
    if (tid < 128) {
        int ql = tid >> 6;            // local quad 0/1
        int ct = (tid >> 4) & 3;
        int nn = tid & 15;
        int col = ct * 16 + nn;
        float w0 = W1[col], w1 = W1[64 + col], w2 = W1[128 + col], w3 = W1[192 + col];
        unsigned short frag[8];
#pragma unroll
        for (int t = 0; t < 8; ++t) {
            int rloc = ql * 8 + t;
            int k = blockIdx.x * 16 + rloc;
            float4 s = ((const float4*)states)[k];
            float acc = s.x * w0 + s.y * w1 + s.z * w2 + s.w * w3;
            frag[t] = f2bf(dls[rloc] * acc);
        }
        uint4 u;
        u.x = (unsigned)frag[0] | ((unsigned)frag[1] << 16);
        u.y = (unsigned)frag[2] | ((unsigned)frag[3] << 16);
        u.z = (unsigned)frag[4] | ((unsigned)frag[5] << 16);
        u.w = (unsigned)frag[6] | ((unsigned)frag[7] << 16);
        int kb = blockIdx.x >> 1;
        int quad = ql + 2 * (blockIdx.x & 1);
        y1[(kb * 4 + ct) * 64 + quad * 16 + nn] = u;
    }
}

// ---------- kernel 2/4: Z_partial[ks] = A_hat-bits @ Y via MFMA ----------
// 64 rows per wave (4 A-frag groups share every B-load). grid = 32 mt x 16 ks
// = 512 blocks x 4 waves; wave = 64 rows x 64 cols, K = 512.
__global__ __launch_bounds__(256) void k_agg(const uint4* __restrict__ y,
                                             const unsigned int* __restrict__ maskb,
                                             float* __restrict__ zp) {
    int tid = threadIdx.x;
    int wv = tid >> 6, L = tid & 63;
    int mt = blockIdx.x >> 4, ks = blockIdx.x & (KSPLIT - 1);
    int n = L & 15, quad = L >> 4;
    int i0 = mt * 256 + wv * 64 + n;
    const unsigned int* mrow0 = maskb + (size_t)i0 * 256 + ks * 16;
    const unsigned int* mrow1 = mrow0 + 16 * 256;
    const unsigned int* mrow2 = mrow0 + 32 * 256;
    const unsigned int* mrow3 = mrow0 + 48 * 256;
    const uint4* yb = y + (size_t)(ks * 16) * 256 + L;   // 16 kb per split

    f32x4 acc[4][4] = {{{0,0,0,0},{0,0,0,0},{0,0,0,0},{0,0,0,0}},
                       {{0,0,0,0},{0,0,0,0},{0,0,0,0},{0,0,0,0}},
                       {{0,0,0,0},{0,0,0,0},{0,0,0,0},{0,0,0,0}},
                       {{0,0,0,0},{0,0,0,0},{0,0,0,0},{0,0,0,0}}};
    uint4 bcur[4];
    unsigned int mw0 = mrow0[0], mw1 = mrow1[0], mw2 = mrow2[0], mw3 = mrow3[0];
#pragma unroll
    for (int ct = 0; ct < 4; ++ct) bcur[ct] = yb[ct * 64];

    for (int kb = 0; kb < 16; ++kb) {
        uint4 bnext[4];
        unsigned int mwn0 = 0, mwn1 = 0, mwn2 = 0, mwn3 = 0;
        if (kb < 15) {
            const uint4* p = yb + (kb + 1) * 256;
#pragma unroll
            for (int ct = 0; ct < 4; ++ct) bnext[ct] = p[ct * 64];
            mwn0 = mrow0[kb + 1]; mwn1 = mrow1[kb + 1];
            mwn2 = mrow2[kb + 1]; mwn3 = mrow3[kb + 1];
        }
        unsigned int by0 = (mw0 >> (quad * 8)) & 0xFFu;
        unsigned int by1 = (mw1 >> (quad * 8)) & 0xFFu;
        unsigned int by2 = (mw2 >> (quad * 8)) & 0xFFu;
        unsigned int by3 = (mw3 >> (quad * 8)) & 0xFFu;
        s16x8 a0, a1, a2, a3;
#pragma unroll
        for (int t = 0; t < 8; ++t) {
            a0[t] = (short)(((by0 >> t) & 1u) ? 0x3F80 : 0);
            a1[t] = (short)(((by1 >> t) & 1u) ? 0x3F80 : 0);
            a2[t] = (short)(((by2 >> t) & 1u) ? 0x3F80 : 0);
            a3[t] = (short)(((by3 >> t) & 1u) ? 0x3F80 : 0);
        }
#pragma unroll
        for (int ct = 0; ct < 4; ++ct) {
            s16x8 b = __builtin_bit_cast(s16x8, bcur[ct]);
            acc[0][ct] = __builtin_amdgcn_mfma_f32_16x16x32_bf16(a0, b, acc[0][ct], 0, 0, 0);
            acc[1][ct] = __builtin_amdgcn_mfma_f32_16x16x32_bf16(a1, b, acc[1][ct], 0, 0, 0);
            acc[2][ct] = __builtin_amdgcn_mfma_f32_16x16x32_bf16(a2, b, acc[2][ct], 0, 0, 0);
            acc[3][ct] = __builtin_amdgcn_mfma_f32_16x16x32_bf16(a3, b, acc[3][ct], 0, 0, 0);
        }
#pragma unroll
        for (int ct = 0; ct < 4; ++ct) bcur[ct] = bnext[ct];
        mw0 = mwn0; mw1 = mwn1; mw2 = mwn2; mw3 = mwn3;
    }
    // D layout: col = lane&15, row = quad*4 + reg
    float* zb = zp + (size_t)ks * (NPTS * 64) + (size_t)(mt * 256 + wv * 64) * 64;
#pragma unroll
    for (int g = 0; g < 4; ++g)
#pragma unroll
        for (int ct = 0; ct < 4; ++ct)
#pragma unroll
            for (int r = 0; r < 4; ++r)
                zb[(g * 16 + quad * 4 + r) * 64 + ct * 16 + n] = acc[g][ct][r];
}

// ---------- kernel 3: h1 = relu(dinv*sum(zp)+b1); Y2 = dinv*(h1 @ W2) frag order ----------
__global__ __launch_bounds__(256) void k_h1y2(const float* __restrict__ zp,
                                              const float* __restrict__ dinv,
                                              const float* __restrict__ b1,
                                              const float* __restrict__ W2,
                                              uint4* __restrict__ y2) {
    __shared__ float w2s[4096];          // 16 KB
    __shared__ float hbuf[8 * 64];       // 2 KB
    __shared__ unsigned short ybuf[8 * 64];  // 1 KB
    int tid = threadIdx.x;
#pragma unroll
    for (int s = 0; s < 16; ++s) w2s[s * 256 + tid] = W2[s * 256 + tid];
    int j0 = blockIdx.x * 8;
#pragma unroll
    for (int e = tid; e < 512; e += 256) {
        int r = e >> 6, c = e & 63;
        int j = j0 + r;
        float z = 0.0f;
#pragma unroll
        for (int s = 0; s < KSPLIT; ++s) z += zp[(size_t)s * (NPTS * 64) + j * 64 + c];
        hbuf[r * 64 + c] = fmaxf(dinv[j] * z + b1[c], 0.0f);
    }
    __syncthreads();
#pragma unroll
    for (int e = tid; e < 512; e += 256) {
        int r = e >> 6, c = e & 63;
        const float* hr = hbuf + r * 64;
        float acc = 0.0f;
#pragma unroll
        for (int m = 0; m < 64; ++m) acc = fmaf(hr[m], w2s[m * 64 + c], acc);
        ybuf[r * 64 + c] = f2bf(dinv[j0 + r] * acc);
    }
    __syncthreads();
    if (tid < 64) {
        int c = tid;
        unsigned short v[8];
#pragma unroll
        for (int r = 0; r < 8; ++r) v[r] = ybuf[r * 64 + c];
        uint4 u;
        u.x = (unsigned)v[0] | ((unsigned)v[1] << 16);
        u.y = (unsigned)v[2] | ((unsigned)v[3] << 16);
        u.z = (unsigned)v[4] | ((unsigned)v[5] << 16);
        u.w = (unsigned)v[6] | ((unsigned)v[7] << 16);
        int kb = j0 >> 5, quad = (j0 >> 3) & 3, ct = c >> 4, nn = c & 15;
        y2[(kb * 4 + ct) * 64 + quad * 16 + nn] = u;
    }
}

// ---------- kernel 5: out[i] = relu(dinv*sum(zp2)+b2) . cw + cb ----------
__global__ __launch_bounds__(256) void k_out(const float* __restrict__ zp,
                                             const float* __restrict__ dinv,
                                             const float* __restrict__ b2,
                                             const float* __restrict__ cw,
                                             const float* __restrict__ cb,
                                             float* __restrict__ out) {
    int tid = threadIdx.x;
    int wv = tid >> 6, L = tid & 63;
    int i = blockIdx.x * 4 + wv;
    int idx = i * 64 + L;
    float z = 0.0f;
#pragma unroll
    for (int s = 0; s < KSPLIT; ++s) z += zp[(size_t)s * (NPTS * 64) + idx];
    float h = fmaxf(dinv[i] * z + b2[L], 0.0f);
    float v = h * cw[L];
#pragma unroll
    for (int off = 32; off > 0; off >>= 1) v += __shfl_down(v, off, 64);
    if (L == 0) out[i] = v + cb[0];
}

// ---------- launch ----------
extern "C" void kernel_launch(void* const* d_in, const int* in_sizes, int n_in,
                              void* d_out, int out_size, void* d_ws, size_t ws_size,
                              hipStream_t stream) {
    const float* states = (const float*)d_in[0];
    const float* W1 = (const float*)d_in[1];
    const float* b1 = (const float*)d_in[2];
    const float* W2 = (const float*)d_in[3];
    const float* b2 = (const float*)d_in[4];
    const float* cw = (const float*)d_in[5];
    const float* cb = (const float*)d_in[6];
    float* out = (float*)d_out;
    float* mout = out + NPTS;  // mask floats follow out[8192]

    char* ws = (char*)d_ws;
    float* dinv               = (float*)(ws);                               // 64 KB
    unsigned long long* maskb = (unsigned long long*)(ws + (1 << 16));      // 8 MiB
    uint4* y1                 = (uint4*)(ws + (1 << 16) + (8 << 20));       // 1 MiB
    uint4* y2                 = (uint4*)(ws + (1 << 16) + (9 << 20));       // 1 MiB
    float* zp                 = (float*)(ws + (1 << 16) + (10 << 20));      // 32 MiB

    hipLaunchKernelGGL(k_mask, dim3(512), dim3(256), 0, stream,
                       states, W1, mout, maskb, dinv, y1);
    hipLaunchKernelGGL(k_agg,  dim3(32 * KSPLIT), dim3(256), 0, stream,
                       y1, (const unsigned int*)maskb, zp);
    hipLaunchKernelGGL(k_h1y2, dim3(1024), dim3(256), 0, stream, zp, dinv, b1, W2, y2);
    hipLaunchKernelGGL(k_agg,  dim3(32 * KSPLIT), dim3(256), 0, stream,
                       y2, (const unsigned int*)maskb, zp);
    hipLaunchKernelGGL(k_out,  dim3(2048), dim3(256), 0, stream, zp, dinv, b2, cw, cb, out);
}

// Round 5
// 350.015 us; speedup vs baseline: 1.0673x; 1.0673x over previous
//
#include <hip/hip_runtime.h>
#include <hip/hip_bf16.h>
#include <stdint.h>

#define NPTS 8192

typedef float f32x4 __attribute__((ext_vector_type(4)));
typedef short s16x8 __attribute__((ext_vector_type(8)));

// bf16 round-to-nearest-even
__device__ __forceinline__ unsigned short f2bf(float f) {
    unsigned int u = __builtin_bit_cast(unsigned int, f);
    u += 0x7FFFu + ((u >> 16) & 1u);
    return (unsigned short)(u >> 16);
}

// Y in exact MFMA-B-fragment order (16x16x32 bf16):
// frag (kb, ct, lane L=quad*16+n): 8 elems k=kb*32+quad*8+t, col=ct*16+n,
// flat uint4 index = (kb*4 + ct)*64 + L. A wave's (kb,ct) read = contiguous 1KB.

// ---------- kernel 1: mask floats + packed bits + dinv + Y1 (fused) ----------
__global__ __launch_bounds__(256) void k_mask(const float* __restrict__ states,
                                              const float* __restrict__ W1,
                                              float* __restrict__ mout,
                                              unsigned long long* __restrict__ maskb,
                                              float* __restrict__ dinv,
                                              uint4* __restrict__ y1) {
    __shared__ float xs[NPTS];  // 32 KB
    __shared__ float ys[NPTS];  // 32 KB
    __shared__ float dls[16];
    int tid = threadIdx.x;
    for (int r = tid; r < NPTS; r += 256) {
        float4 s = ((const float4*)states)[r];
        xs[r] = s.x; ys[r] = s.y;
    }
    __syncthreads();
    int wv = tid >> 6, L = tid & 63;
    int rowbase = blockIdx.x * 16 + wv * 4;
    float xi[4], yi[4];
    int deg[4] = {0, 0, 0, 0};
#pragma unroll
    for (int rr = 0; rr < 4; ++rr) { xi[rr] = xs[rowbase + rr]; yi[rr] = ys[rowbase + rr]; }
    for (int it = 0; it < 128; ++it) {
        int j = it * 64 + L;
        float xj = xs[j], yj = ys[j];
#pragma unroll
        for (int rr = 0; rr < 4; ++rr) {
            float dx = xi[rr] - xj;
            float dy = yi[rr] - yj;
            // must match numpy fp32 (dx*dx)+(dy*dy), no FMA contraction:
            float d2 = __fadd_rn(__fmul_rn(dx, dx), __fmul_rn(dy, dy));
            bool pred = (d2 <= 1.0f);
            __builtin_nontemporal_store(pred ? 1.0f : 0.0f,
                                        &mout[(size_t)(rowbase + rr) * NPTS + j]);
            unsigned long long b = __ballot(pred);
            if (L == 0) maskb[(size_t)(rowbase + rr) * 128 + it] = b;
            deg[rr] += (int)__popcll(b);
        }
    }
    if (L == 0) {
#pragma unroll
        for (int rr = 0; rr < 4; ++rr) {
            float dv = rsqrtf((float)deg[rr]);
            dinv[rowbase + rr] = dv;
            dls[wv * 4 + rr] = dv;
        }
    }
    __syncthreads();
    // Y1: 128 threads produce this block's 128 uint4 fragments
    if (tid < 128) {
        int ql = tid >> 6;            // local quad 0/1
        int ct = (tid >> 4) & 3;
        int nn = tid & 15;
        int col = ct * 16 + nn;
        float w0 = W1[col], w1 = W1[64 + col], w2 = W1[128 + col], w3 = W1[192 + col];
        unsigned short frag[8];
#pragma unroll
        for (int t = 0; t < 8; ++t) {
            int rloc = ql * 8 + t;
            int k = blockIdx.x * 16 + rloc;
            float4 s = ((const float4*)states)[k];
            float acc = s.x * w0 + s.y * w1 + s.z * w2 + s.w * w3;
            frag[t] = f2bf(dls[rloc] * acc);
        }
        uint4 u;
        u.x = (unsigned)frag[0] | ((unsigned)frag[1] << 16);
        u.y = (unsigned)frag[2] | ((unsigned)frag[3] << 16);
        u.z = (unsigned)frag[4] | ((unsigned)frag[5] << 16);
        u.w = (unsigned)frag[6] | ((unsigned)frag[7] << 16);
        int kb = blockIdx.x >> 1;
        int quad = ql + 2 * (blockIdx.x & 1);
        y1[(kb * 4 + ct) * 64 + quad * 16 + nn] = u;
    }
}

// ---------- shared agg core: full-K aggregation for 32 rows + reduce + relu ----------
// 512 threads, 8 waves; wave w covers K-chunk [w*1024,(w+1)*1024).
// Leaves h (post-relu, post-bias, post-dinv) in hbuf[32][66].
__device__ __forceinline__ void agg_core(const uint4* __restrict__ y,
                                         const unsigned int* __restrict__ maskb,
                                         const float* __restrict__ dinv,
                                         const float* __restrict__ bias,
                                         float* __restrict__ redbuf,   // [8*2048]
                                         float* __restrict__ hbuf,     // [32*66]
                                         int R0) {
    int tid = threadIdx.x;
    int w = tid >> 6, L = tid & 63;
    int n = L & 15, quad = L >> 4;
    const unsigned int* mrow0 = maskb + (size_t)(R0 + n) * 256 + w * 32;
    const unsigned int* mrow1 = mrow0 + 16 * 256;
    const uint4* yb = y + (size_t)w * 8192 + L;

    f32x4 acc[2][4] = {{{0,0,0,0},{0,0,0,0},{0,0,0,0},{0,0,0,0}},
                       {{0,0,0,0},{0,0,0,0},{0,0,0,0},{0,0,0,0}}};
    uint4 bcur[4];
    unsigned int mw0 = mrow0[0], mw1 = mrow1[0];
#pragma unroll
    for (int ct = 0; ct < 4; ++ct) bcur[ct] = yb[ct * 64];

    for (int kk = 0; kk < 32; ++kk) {
        uint4 bnext[4];
        unsigned int mwn0 = 0, mwn1 = 0;
        if (kk < 31) {
            const uint4* p = yb + (kk + 1) * 256;
#pragma unroll
            for (int ct = 0; ct < 4; ++ct) bnext[ct] = p[ct * 64];
            mwn0 = mrow0[kk + 1]; mwn1 = mrow1[kk + 1];
        }
        unsigned int by0 = (mw0 >> (quad * 8)) & 0xFFu;
        unsigned int by1 = (mw1 >> (quad * 8)) & 0xFFu;
        s16x8 a0, a1;
#pragma unroll
        for (int t = 0; t < 8; ++t) {
            a0[t] = (short)(((by0 >> t) & 1u) ? 0x3F80 : 0);
            a1[t] = (short)(((by1 >> t) & 1u) ? 0x3F80 : 0);
        }
#pragma unroll
        for (int ct = 0; ct < 4; ++ct) {
            s16x8 b = __builtin_bit_cast(s16x8, bcur[ct]);
            acc[0][ct] = __builtin_amdgcn_mfma_f32_16x16x32_bf16(a0, b, acc[0][ct], 0, 0, 0);
            acc[1][ct] = __builtin_amdgcn_mfma_f32_16x16x32_bf16(a1, b, acc[1][ct], 0, 0, 0);
        }
#pragma unroll
        for (int ct = 0; ct < 4; ++ct) bcur[ct] = bnext[ct];
        mw0 = mwn0; mw1 = mwn1;
    }
    // dump partials: D layout col = lane&15, row = quad*4 + reg
    float* rb = redbuf + w * 2048;
#pragma unroll
    for (int g = 0; g < 2; ++g)
#pragma unroll
        for (int ct = 0; ct < 4; ++ct)
#pragma unroll
            for (int r = 0; r < 4; ++r)
                rb[(g * 16 + quad * 4 + r) * 64 + ct * 16 + n] = acc[g][ct][r];
    __syncthreads();
    // reduce 8 partials + bias + relu -> hbuf
    for (int e = tid; e < 2048; e += 512) {
        float z = 0.0f;
#pragma unroll
        for (int ww = 0; ww < 8; ++ww) z += redbuf[ww * 2048 + e];
        int row = e >> 6, col = e & 63;
        hbuf[row * 66 + col] = fmaxf(dinv[R0 + row] * z + bias[col], 0.0f);
    }
    __syncthreads();
}

// ---------- kernel 2: layer 1 agg + h1 + Y2 fragments (fused) ----------
__global__ __launch_bounds__(512) void k_layer1(const uint4* __restrict__ y1,
                                                const unsigned int* __restrict__ maskb,
                                                const float* __restrict__ dinv,
                                                const float* __restrict__ b1,
                                                const float* __restrict__ W2,
                                                uint4* __restrict__ y2) {
    __shared__ float redbuf[8 * 2048];   // 64 KB
    __shared__ float hbuf[32 * 66];      // 8.25 KB
    __shared__ float w2s[4096];          // 16 KB
    int tid = threadIdx.x;
    for (int s = tid; s < 4096; s += 512) w2s[s] = W2[s];
    int R0 = blockIdx.x * 32;
    agg_core(y1, maskb, dinv, b1, redbuf, hbuf, R0);
    // y2 = dinv * (h1 @ W2), written straight into fragment order.
    // Block's 32 rows = exactly kb block blockIdx.x.
    if (tid < 256) {
        int nn = tid & 15, q = (tid >> 4) & 3, ct = tid >> 6;
        int col = ct * 16 + nn;
        float dot[8] = {0, 0, 0, 0, 0, 0, 0, 0};
        for (int m = 0; m < 64; ++m) {
            float wv = w2s[m * 64 + col];
#pragma unroll
            for (int t = 0; t < 8; ++t)
                dot[t] = fmaf(hbuf[(q * 8 + t) * 66 + m], wv, dot[t]);
        }
        unsigned short v[8];
#pragma unroll
        for (int t = 0; t < 8; ++t) v[t] = f2bf(dinv[R0 + q * 8 + t] * dot[t]);
        uint4 u;
        u.x = (unsigned)v[0] | ((unsigned)v[1] << 16);
        u.y = (unsigned)v[2] | ((unsigned)v[3] << 16);
        u.z = (unsigned)v[4] | ((unsigned)v[5] << 16);
        u.w = (unsigned)v[6] | ((unsigned)v[7] << 16);
        y2[(blockIdx.x * 4 + ct) * 64 + q * 16 + nn] = u;
    }
}

// ---------- kernel 3: layer 2 agg + h2 + scalar head (fused) ----------
__global__ __launch_bounds__(512) void k_layer2(const uint4* __restrict__ y2,
                                                const unsigned int* __restrict__ maskb,
                                                const float* __restrict__ dinv,
                                                const float* __restrict__ b2,
                                                const float* __restrict__ cw,
                                                const float* __restrict__ cb,
                                                float* __restrict__ out) {
    __shared__ float redbuf[8 * 2048];   // 64 KB
    __shared__ float hbuf[32 * 66];      // 8.25 KB
    __shared__ float cws[64];
    int tid = threadIdx.x;
    if (tid < 64) cws[tid] = cw[tid];
    int R0 = blockIdx.x * 32;
    agg_core(y2, maskb, dinv, b2, redbuf, hbuf, R0);
    // out[i] = h2[i,:] . cw + cb ; 512 threads = 32 rows x 16 groups of 4 cols
    int row = tid >> 4, cg = tid & 15;
    float v = 0.0f;
#pragma unroll
    for (int e = 0; e < 4; ++e) {
        int c = cg * 4 + e;
        v = fmaf(hbuf[row * 66 + c], cws[c], v);
    }
    // segmented reduce over the 16 lanes of each row-group
    v += __shfl_down(v, 8);
    v += __shfl_down(v, 4);
    v += __shfl_down(v, 2);
    v += __shfl_down(v, 1);
    if (cg == 0) out[R0 + row] = v + cb[0];
}

// ---------- launch ----------
extern "C" void kernel_launch(void* const* d_in, const int* in_sizes, int n_in,
                              void* d_out, int out_size, void* d_ws, size_t ws_size,
                              hipStream_t stream) {
    const float* states = (const float*)d_in[0];
    const float* W1 = (const float*)d_in[1];
    const float* b1 = (const float*)d_in[2];
    const float* W2 = (const float*)d_in[3];
    const float* b2 = (const float*)d_in[4];
    const float* cw = (const float*)d_in[5];
    const float* cb = (const float*)d_in[6];
    float* out = (float*)d_out;
    float* mout = out + NPTS;  // mask floats follow out[8192]

    char* ws = (char*)d_ws;
    float* dinv               = (float*)(ws);                          // 64 KB
    unsigned long long* maskb = (unsigned long long*)(ws + (1 << 16)); // 8 MiB
    uint4* y1                 = (uint4*)(ws + (1 << 16) + (8 << 20));  // 1 MiB
    uint4* y2                 = (uint4*)(ws + (1 << 16) + (9 << 20));  // 1 MiB

    hipLaunchKernelGGL(k_mask,   dim3(512), dim3(256), 0, stream,
                       states, W1, mout, maskb, dinv, y1);
    hipLaunchKernelGGL(k_layer1, dim3(256), dim3(512), 0, stream,
                       y1, (const unsigned int*)maskb, dinv, b1, W2, y2);
    hipLaunchKernelGGL(k_layer2, dim3(256), dim3(512), 0, stream,
                       y2, (const unsigned int*)maskb, dinv, b2, cw, cb, out);
}

// Round 6
// 334.318 us; speedup vs baseline: 1.1174x; 1.0470x over previous
//
#include <hip/hip_runtime.h>
#include <hip/hip_bf16.h>
#include <stdint.h>

#define NPTS 8192
#define MSTRIDE 260   // LDS mask row stride in dwords (16B-aligned, conflict-free)

typedef float f32x4 __attribute__((ext_vector_type(4)));
typedef short s16x8 __attribute__((ext_vector_type(8)));

// bf16 round-to-nearest-even
__device__ __forceinline__ unsigned short f2bf(float f) {
    unsigned int u = __builtin_bit_cast(unsigned int, f);
    u += 0x7FFFu + ((u >> 16) & 1u);
    return (unsigned short)(u >> 16);
}

// Y in exact MFMA-B-fragment order (16x16x32 bf16):
// frag (kb, ct, lane L=quad*16+n): 8 elems k=kb*32+quad*8+t, col=ct*16+n,
// flat uint4 index = (kb*4 + ct)*64 + L. A wave's (kb,ct) read = contiguous 1KB.

// ---------- kernel 1: mask floats + packed bits + dinv + Y1 (fused) ----------
__global__ __launch_bounds__(256) void k_mask(const float* __restrict__ states,
                                              const float* __restrict__ W1,
                                              float* __restrict__ mout,
                                              unsigned long long* __restrict__ maskb,
                                              float* __restrict__ dinv,
                                              uint4* __restrict__ y1) {
    __shared__ float xs[NPTS];  // 32 KB
    __shared__ float ys[NPTS];  // 32 KB
    __shared__ float dls[16];
    int tid = threadIdx.x;
    for (int r = tid; r < NPTS; r += 256) {
        float4 s = ((const float4*)states)[r];
        xs[r] = s.x; ys[r] = s.y;
    }
    __syncthreads();
    int wv = tid >> 6, L = tid & 63;
    int rowbase = blockIdx.x * 16 + wv * 4;
    float xi[4], yi[4];
    int deg[4] = {0, 0, 0, 0};
#pragma unroll
    for (int rr = 0; rr < 4; ++rr) { xi[rr] = xs[rowbase + rr]; yi[rr] = ys[rowbase + rr]; }
    for (int it = 0; it < 128; ++it) {
        int j = it * 64 + L;
        float xj = xs[j], yj = ys[j];
#pragma unroll
        for (int rr = 0; rr < 4; ++rr) {
            float dx = xi[rr] - xj;
            float dy = yi[rr] - yj;
            // must match numpy fp32 (dx*dx)+(dy*dy), no FMA contraction:
            float d2 = __fadd_rn(__fmul_rn(dx, dx), __fmul_rn(dy, dy));
            bool pred = (d2 <= 1.0f);
            __builtin_nontemporal_store(pred ? 1.0f : 0.0f,
                                        &mout[(size_t)(rowbase + rr) * NPTS + j]);
            unsigned long long b = __ballot(pred);
            if (L == 0) maskb[(size_t)(rowbase + rr) * 128 + it] = b;
            deg[rr] += (int)__popcll(b);
        }
    }
    if (L == 0) {
#pragma unroll
        for (int rr = 0; rr < 4; ++rr) {
            float dv = rsqrtf((float)deg[rr]);
            dinv[rowbase + rr] = dv;
            dls[wv * 4 + rr] = dv;
        }
    }
    __syncthreads();
    // Y1: 128 threads produce this block's 128 uint4 fragments
    if (tid < 128) {
        int ql = tid >> 6;            // local quad 0/1
        int ct = (tid >> 4) & 3;
        int nn = tid & 15;
        int col = ct * 16 + nn;
        float w0 = W1[col], w1 = W1[64 + col], w2 = W1[128 + col], w3 = W1[192 + col];
        unsigned short frag[8];
#pragma unroll
        for (int t = 0; t < 8; ++t) {
            int rloc = ql * 8 + t;
            int k = blockIdx.x * 16 + rloc;
            float4 s = ((const float4*)states)[k];
            float acc = s.x * w0 + s.y * w1 + s.z * w2 + s.w * w3;
            frag[t] = f2bf(dls[rloc] * acc);
        }
        uint4 u;
        u.x = (unsigned)frag[0] | ((unsigned)frag[1] << 16);
        u.y = (unsigned)frag[2] | ((unsigned)frag[3] << 16);
        u.z = (unsigned)frag[4] | ((unsigned)frag[5] << 16);
        u.w = (unsigned)frag[6] | ((unsigned)frag[7] << 16);
        int kb = blockIdx.x >> 1;
        int quad = ql + 2 * (blockIdx.x & 1);
        y1[(kb * 4 + ct) * 64 + quad * 16 + nn] = u;
    }
}

// ---------- shared agg core: full-K aggregation for 32 rows + reduce + relu ----------
// 512 threads, 8 waves; wave w covers K-chunk [w*1024,(w+1)*1024).
// Mask rows staged in LDS up front (kills per-iter HBM dword stalls).
// Leaves h (post-relu, post-bias, post-dinv) in hbuf[32][66].
__device__ __forceinline__ void agg_core(const uint4* __restrict__ y,
                                         const unsigned int* __restrict__ maskb,
                                         const float* __restrict__ dinv,
                                         const float* __restrict__ bias,
                                         float* __restrict__ redbuf,        // [8*2048]
                                         unsigned int* __restrict__ mlds,   // [32*MSTRIDE]
                                         float* __restrict__ hbuf,          // [32*66]
                                         int R0) {
    int tid = threadIdx.x;
    // ---- stage 32 mask rows (32 KB) into LDS with coalesced dwordx4 ----
    {
        const uint4* src = (const uint4*)(maskb + (size_t)R0 * 256);
        for (int e = tid; e < 2048; e += 512) {
            uint4 v = src[e];
            int r = e >> 6, c4 = e & 63;
            *(uint4*)(mlds + r * MSTRIDE + c4 * 4) = v;
        }
    }
    __syncthreads();
    int w = tid >> 6, L = tid & 63;
    int n = L & 15, quad = L >> 4;
    const unsigned int* mr0 = mlds + n * MSTRIDE + w * 32;
    const unsigned int* mr1 = mr0 + 16 * MSTRIDE;
    const uint4* yb = y + (size_t)w * 8192 + L;

    f32x4 acc[2][4] = {{{0,0,0,0},{0,0,0,0},{0,0,0,0},{0,0,0,0}},
                       {{0,0,0,0},{0,0,0,0},{0,0,0,0},{0,0,0,0}}};
    uint4 b0[4], b1[4];
#pragma unroll
    for (int ct = 0; ct < 4; ++ct) b0[ct] = yb[ct * 64];
#pragma unroll
    for (int ct = 0; ct < 4; ++ct) b1[ct] = yb[256 + ct * 64];

    for (int kk = 0; kk < 32; kk += 2) {
        uint4 bn[4];
        // even step: compute with b0, prefetch kk+2
        if (kk + 2 < 32) {
            const uint4* p = yb + (kk + 2) * 256;
#pragma unroll
            for (int ct = 0; ct < 4; ++ct) bn[ct] = p[ct * 64];
        }
        {
            unsigned int mw0 = mr0[kk], mw1 = mr1[kk];
            unsigned int by0 = (mw0 >> (quad * 8)) & 0xFFu;
            unsigned int by1 = (mw1 >> (quad * 8)) & 0xFFu;
            s16x8 a0, a1;
#pragma unroll
            for (int t = 0; t < 8; ++t) {
                a0[t] = (short)(((by0 >> t) & 1u) ? 0x3F80 : 0);
                a1[t] = (short)(((by1 >> t) & 1u) ? 0x3F80 : 0);
            }
#pragma unroll
            for (int ct = 0; ct < 4; ++ct) {
                s16x8 b = __builtin_bit_cast(s16x8, b0[ct]);
                acc[0][ct] = __builtin_amdgcn_mfma_f32_16x16x32_bf16(a0, b, acc[0][ct], 0, 0, 0);
                acc[1][ct] = __builtin_amdgcn_mfma_f32_16x16x32_bf16(a1, b, acc[1][ct], 0, 0, 0);
            }
        }
#pragma unroll
        for (int ct = 0; ct < 4; ++ct) b0[ct] = bn[ct];
        // odd step: compute with b1, prefetch kk+3
        if (kk + 3 < 32) {
            const uint4* p = yb + (kk + 3) * 256;
#pragma unroll
            for (int ct = 0; ct < 4; ++ct) bn[ct] = p[ct * 64];
        }
        {
            unsigned int mw0 = mr0[kk + 1], mw1 = mr1[kk + 1];
            unsigned int by0 = (mw0 >> (quad * 8)) & 0xFFu;
            unsigned int by1 = (mw1 >> (quad * 8)) & 0xFFu;
            s16x8 a0, a1;
#pragma unroll
            for (int t = 0; t < 8; ++t) {
                a0[t] = (short)(((by0 >> t) & 1u) ? 0x3F80 : 0);
                a1[t] = (short)(((by1 >> t) & 1u) ? 0x3F80 : 0);
            }
#pragma unroll
            for (int ct = 0; ct < 4; ++ct) {
                s16x8 b = __builtin_bit_cast(s16x8, b1[ct]);
                acc[0][ct] = __builtin_amdgcn_mfma_f32_16x16x32_bf16(a0, b, acc[0][ct], 0, 0, 0);
                acc[1][ct] = __builtin_amdgcn_mfma_f32_16x16x32_bf16(a1, b, acc[1][ct], 0, 0, 0);
            }
        }
#pragma unroll
        for (int ct = 0; ct < 4; ++ct) b1[ct] = bn[ct];
    }
    // dump partials: D layout col = lane&15, row = quad*4 + reg
    float* rb = redbuf + w * 2048;
#pragma unroll
    for (int g = 0; g < 2; ++g)
#pragma unroll
        for (int ct = 0; ct < 4; ++ct)
#pragma unroll
            for (int r = 0; r < 4; ++r)
                rb[(g * 16 + quad * 4 + r) * 64 + ct * 16 + n] = acc[g][ct][r];
    __syncthreads();
    // reduce 8 partials + bias + relu -> hbuf
    for (int e = tid; e < 2048; e += 512) {
        float z = 0.0f;
#pragma unroll
        for (int ww = 0; ww < 8; ++ww) z += redbuf[ww * 2048 + e];
        int row = e >> 6, col = e & 63;
        hbuf[row * 66 + col] = fmaxf(dinv[R0 + row] * z + bias[col], 0.0f);
    }
    __syncthreads();
}

// ---------- kernel 2: layer 1 agg + h1 + Y2 fragments (fused) ----------
__global__ __launch_bounds__(512) void k_layer1(const uint4* __restrict__ y1,
                                                const unsigned int* __restrict__ maskb,
                                                const float* __restrict__ dinv,
                                                const float* __restrict__ b1,
                                                const float* __restrict__ W2,
                                                uint4* __restrict__ y2) {
    __shared__ float redbuf[8 * 2048];             // 64 KB
    __shared__ unsigned int mlds[32 * MSTRIDE];    // 32.5 KB
    __shared__ float hbuf[32 * 66];                // 8.25 KB
    __shared__ float w2s[4096];                    // 16 KB
    int tid = threadIdx.x;
    for (int s = tid; s < 4096; s += 512) w2s[s] = W2[s];
    int R0 = blockIdx.x * 32;
    agg_core(y1, maskb, dinv, b1, redbuf, mlds, hbuf, R0);
    // y2 = dinv * (h1 @ W2), written straight into fragment order (all 512 thr).
    {
        int nn = tid & 15, q = (tid >> 4) & 3, ct = (tid >> 6) & 3, half = tid >> 8;
        int col = ct * 16 + nn;
        float dot[4] = {0, 0, 0, 0};
        for (int m = 0; m < 64; ++m) {
            float wv = w2s[m * 64 + col];
#pragma unroll
            for (int t = 0; t < 4; ++t)
                dot[t] = fmaf(hbuf[(q * 8 + half * 4 + t) * 66 + m], wv, dot[t]);
        }
        unsigned short v[4];
#pragma unroll
        for (int t = 0; t < 4; ++t) v[t] = f2bf(dinv[R0 + q * 8 + half * 4 + t] * dot[t]);
        uint2 u;
        u.x = (unsigned)v[0] | ((unsigned)v[1] << 16);
        u.y = (unsigned)v[2] | ((unsigned)v[3] << 16);
        int fragidx = (blockIdx.x * 4 + ct) * 64 + q * 16 + nn;
        ((uint2*)y2)[fragidx * 2 + half] = u;
    }
}

// ---------- kernel 3: layer 2 agg + h2 + scalar head (fused) ----------
__global__ __launch_bounds__(512) void k_layer2(const uint4* __restrict__ y2,
                                                const unsigned int* __restrict__ maskb,
                                                const float* __restrict__ dinv,
                                                const float* __restrict__ b2,
                                                const float* __restrict__ cw,
                                                const float* __restrict__ cb,
                                                float* __restrict__ out) {
    __shared__ float redbuf[8 * 2048];             // 64 KB
    __shared__ unsigned int mlds[32 * MSTRIDE];    // 32.5 KB
    __shared__ float hbuf[32 * 66];                // 8.25 KB
    __shared__ float cws[64];
    int tid = threadIdx.x;
    if (tid < 64) cws[tid] = cw[tid];
    int R0 = blockIdx.x * 32;
    agg_core(y2, maskb, dinv, b2, redbuf, mlds, hbuf, R0);
    // out[i] = h2[i,:] . cw + cb ; 512 threads = 32 rows x 16 groups of 4 cols
    int row = tid >> 4, cg = tid & 15;
    float v = 0.0f;
#pragma unroll
    for (int e = 0; e < 4; ++e) {
        int c = cg * 4 + e;
        v = fmaf(hbuf[row * 66 + c], cws[c], v);
    }
    v += __shfl_down(v, 8);
    v += __shfl_down(v, 4);
    v += __shfl_down(v, 2);
    v += __shfl_down(v, 1);
    if (cg == 0) out[R0 + row] = v + cb[0];
}

// ---------- launch ----------
extern "C" void kernel_launch(void* const* d_in, const int* in_sizes, int n_in,
                              void* d_out, int out_size, void* d_ws, size_t ws_size,
                              hipStream_t stream) {
    const float* states = (const float*)d_in[0];
    const float* W1 = (const float*)d_in[1];
    const float* b1 = (const float*)d_in[2];
    const float* W2 = (const float*)d_in[3];
    const float* b2 = (const float*)d_in[4];
    const float* cw = (const float*)d_in[5];
    const float* cb = (const float*)d_in[6];
    float* out = (float*)d_out;
    float* mout = out + NPTS;  // mask floats follow out[8192]

    char* ws = (char*)d_ws;
    float* dinv               = (float*)(ws);                          // 64 KB
    unsigned long long* maskb = (unsigned long long*)(ws + (1 << 16)); // 8 MiB
    uint4* y1                 = (uint4*)(ws + (1 << 16) + (8 << 20));  // 1 MiB
    uint4* y2                 = (uint4*)(ws + (1 << 16) + (9 << 20));  // 1 MiB

    hipLaunchKernelGGL(k_mask,   dim3(512), dim3(256), 0, stream,
                       states, W1, mout, maskb, dinv, y1);
    hipLaunchKernelGGL(k_layer1, dim3(256), dim3(512), 0, stream,
                       y1, (const unsigned int*)maskb, dinv, b1, W2, y2);
    hipLaunchKernelGGL(k_layer2, dim3(256), dim3(512), 0, stream,
                       y2, (const unsigned int*)maskb, dinv, b2, cw, cb, out);
}